// Round 2
// baseline (387.043 us; speedup 1.0000x reference)
//
#include <hip/hip_runtime.h>
#include <cstdint>
#include <cmath>

// Problem constants: B=2, F=5, C=256, H=64, W=64, HN=8, hd=16
// Token layout: n = (b*5+f)*4096 + h*64 + w, N = 40960 tokens, channels-last.

typedef __bf16 bf16x8 __attribute__((ext_vector_type(8)));
typedef float f32x4 __attribute__((ext_vector_type(4)));

__device__ __forceinline__ unsigned short f2bf(float f) {
    union { float f; unsigned int u; } v; v.f = f;
    unsigned int r = (v.u + 0x7fffu + ((v.u >> 16) & 1u)) >> 16;
    return (unsigned short)r;
}
__device__ __forceinline__ float bf2f(unsigned short h) {
    union { unsigned int u; float f; } v; v.u = ((unsigned int)h) << 16;
    return v.f;
}

// ---------------- weight fp32 -> bf16 ----------------
__global__ void cvt_kernel(const float* __restrict__ src, unsigned short* __restrict__ dst, int n) {
    int i = blockIdx.x * 256 + threadIdx.x;
    if (i < n) dst[i] = f2bf(src[i]);
}

// ---------------- LN1: x (B,F,C,H,W) -> xn bf16 (N,256) + xt bf16 (N,256) ----------------
// One block per (b*F+f, h) row: 64 tokens (w) x 256 channels, transposed via LDS.
__global__ __launch_bounds__(256) void ln1_kernel(const float* __restrict__ x,
                                                  const float* __restrict__ g,
                                                  const float* __restrict__ bta,
                                                  unsigned short* __restrict__ xn,
                                                  unsigned short* __restrict__ xt) {
    __shared__ unsigned short tile[64 * 257];   // [w][c], padded stride
    __shared__ float psum[4][64], psq[4][64], meanL[64], rstdL[64];
    int bx = blockIdx.x;
    int bf = bx >> 6, h = bx & 63;              // bf = b*5+f
    size_t base = (size_t)bf * 1048576 + (size_t)h * 64;  // x[bf, c=0, h, w=0]
    int tid = threadIdx.x;
    int w = tid & 63, cg = tid >> 6;
    float s = 0.f, sq = 0.f;
    for (int k = 0; k < 64; ++k) {
        int c = cg * 64 + k;
        float v = x[base + (size_t)c * 4096 + w];   // lanes vary w -> coalesced
        s += v; sq += v * v;
        tile[w * 257 + c] = f2bf(v);
    }
    psum[cg][w] = s; psq[cg][w] = sq;
    __syncthreads();
    if (tid < 64) {
        float ss = psum[0][tid] + psum[1][tid] + psum[2][tid] + psum[3][tid];
        float qq = psq[0][tid] + psq[1][tid] + psq[2][tid] + psq[3][tid];
        float mean = ss * (1.f / 256.f);
        float var = qq * (1.f / 256.f) - mean * mean;
        meanL[tid] = mean;
        rstdL[tid] = rsqrtf(var + 1e-5f);
    }
    __syncthreads();
    int n0 = bf * 4096 + h * 64;
    float gc = g[tid], bc = bta[tid];           // tid == channel in pass 2
    for (int rep = 0; rep < 64; ++rep) {        // rep == token w
        unsigned short raw = tile[rep * 257 + tid];
        float v = bf2f(raw);
        float o = (v - meanL[rep]) * rstdL[rep] * gc + bc;
        size_t oi = (size_t)(n0 + rep) * 256 + tid;   // coalesced
        xn[oi] = f2bf(o);
        xt[oi] = raw;
    }
}

// ---------------- generic bf16 MFMA GEMM: C(MxN) = A(MxK) * B(NxK)^T (+epilogue) ----------------
// modes: 0 = bias, store bf16
//        1 = bias + res(bf16, ldc) , store bf16        (attn proj + x residual)
//        2 = bias + exact GELU, store bf16             (FFN1)
//        3 = bias + res(bf16, 256) , store fp32 transposed to (B,F,C,H,W)  (FFN2 + out)
__global__ __launch_bounds__(256) void gemm_kernel(const unsigned short* __restrict__ A, int lda,
                                                   const unsigned short* __restrict__ B,
                                                   const float* __restrict__ bias,
                                                   unsigned short* __restrict__ C, int ldc,
                                                   const unsigned short* __restrict__ res,
                                                   float* __restrict__ outT,
                                                   int K, int mode) {
    __shared__ __align__(16) unsigned short As[64 * 40];  // stride 40 shorts (80 B, 16B-aligned rows)
    __shared__ __align__(16) unsigned short Bs[64 * 40];
    int tid = threadIdx.x;
    int m0 = blockIdx.y * 64, n0 = blockIdx.x * 64;
    int row = tid >> 2, seg = tid & 3;                    // staging: 4 threads/row, 8 bf16 each
    int lane = tid & 63, wvid = tid >> 6;
    int wm = wvid >> 1, wn = wvid & 1;                    // 2x2 waves, 32x32 per wave
    int r16 = lane & 15, kg = lane >> 4;
    f32x4 acc[2][2] = {};
    const unsigned short* Abase = A + (size_t)(m0 + row) * lda + seg * 8;
    const unsigned short* Bbase = B + (size_t)(n0 + row) * K + seg * 8;
    for (int k0 = 0; k0 < K; k0 += 32) {
        *(uint4*)&As[row * 40 + seg * 8] = *(const uint4*)(Abase + k0);
        *(uint4*)&Bs[row * 40 + seg * 8] = *(const uint4*)(Bbase + k0);
        __syncthreads();
        bf16x8 a0 = *(const bf16x8*)&As[(wm * 32 + r16) * 40 + kg * 8];
        bf16x8 a1 = *(const bf16x8*)&As[(wm * 32 + 16 + r16) * 40 + kg * 8];
        bf16x8 b0 = *(const bf16x8*)&Bs[(wn * 32 + r16) * 40 + kg * 8];
        bf16x8 b1 = *(const bf16x8*)&Bs[(wn * 32 + 16 + r16) * 40 + kg * 8];
        acc[0][0] = __builtin_amdgcn_mfma_f32_16x16x32_bf16(a0, b0, acc[0][0], 0, 0, 0);
        acc[0][1] = __builtin_amdgcn_mfma_f32_16x16x32_bf16(a0, b1, acc[0][1], 0, 0, 0);
        acc[1][0] = __builtin_amdgcn_mfma_f32_16x16x32_bf16(a1, b0, acc[1][0], 0, 0, 0);
        acc[1][1] = __builtin_amdgcn_mfma_f32_16x16x32_bf16(a1, b1, acc[1][1], 0, 0, 0);
        __syncthreads();
    }
    int rowBase = (lane >> 4) * 4;
    for (int i = 0; i < 2; ++i) {
        for (int j = 0; j < 2; ++j) {
            #pragma unroll
            for (int r = 0; r < 4; ++r) {
                int m = m0 + wm * 32 + i * 16 + rowBase + r;    // token row
                int n = n0 + wn * 32 + j * 16 + r16;            // output channel
                float v = acc[i][j][r] + bias[n];
                if (mode == 1) v += bf2f(res[(size_t)m * ldc + n]);
                else if (mode == 2) v = 0.5f * v * (1.0f + erff(v * 0.70710678118f));
                if (mode == 3) {
                    v += bf2f(res[(size_t)m * 256 + n]);
                    int bfi = m >> 12, hh = (m >> 6) & 63, ww = m & 63;
                    outT[(size_t)bfi * 1048576 + (size_t)n * 4096 + hh * 64 + ww] = v;
                } else {
                    C[(size_t)m * ldc + n] = f2bf(v);
                }
            }
        }
    }
}

// ---------------- attention: per (b, head, line) group; seq F=5, feat 1024 ----------------
__global__ __launch_bounds__(256) void attn_kernel(const unsigned short* __restrict__ qkv,
                                                   unsigned short* __restrict__ ao,
                                                   int vertical) {
    __shared__ unsigned short qL[5 * 1024], kL[5 * 1024], vL[5 * 1024];
    __shared__ float sL[25];
    int g = blockIdx.x;
    int lw = g & 63;            // h (horizontal) or w (vertical)
    int head = (g >> 6) & 7;
    int b = g >> 9;
    int tid = threadIdx.x;
    for (int idx = tid; idx < 5120; idx += 256) {
        int f = idx >> 10, j = idx & 1023;
        int pos = j >> 4, d = j & 15;       // j = pos*16 + d ; pos = w (horiz) or h (vert)
        size_t n = (size_t)b * 20480 + (size_t)f * 4096 +
                   (vertical ? (pos * 64 + lw) : (lw * 64 + pos));
        size_t src = n * 384 + head * 16 + d;
        qL[idx] = qkv[src];
        kL[idx] = qkv[src + 128];
        vL[idx] = qkv[src + 256];
    }
    __syncthreads();
    int lane = tid & 63, wwv = tid >> 6;
    for (int p = wwv; p < 25; p += 4) {
        int qf = p / 5, kf = p - qf * 5;
        float acc = 0.f;
        const unsigned short* qp = &qL[qf * 1024 + lane * 16];
        const unsigned short* kp = &kL[kf * 1024 + lane * 16];
        #pragma unroll
        for (int t = 0; t < 16; ++t) acc += bf2f(qp[t]) * bf2f(kp[t]);
        for (int off = 32; off; off >>= 1) acc += __shfl_down(acc, off);
        if (lane == 0) sL[p] = acc * 0.03125f;   // 1/sqrt(1024)
    }
    __syncthreads();
    if (tid < 5) {
        float mx = -1e30f;
        for (int kf = 0; kf < 5; ++kf) mx = fmaxf(mx, sL[tid * 5 + kf]);
        float e[5], sum = 0.f;
        for (int kf = 0; kf < 5; ++kf) { e[kf] = expf(sL[tid * 5 + kf] - mx); sum += e[kf]; }
        float inv = 1.f / sum;
        for (int kf = 0; kf < 5; ++kf) sL[tid * 5 + kf] = e[kf] * inv;
    }
    __syncthreads();
    int coff = vertical ? 128 : 0;
    for (int idx = tid; idx < 5120; idx += 256) {
        int qf = idx >> 10, j = idx & 1023;
        int pos = j >> 4, d = j & 15;
        float acc = 0.f;
        #pragma unroll
        for (int kf = 0; kf < 5; ++kf) acc += sL[qf * 5 + kf] * bf2f(vL[kf * 1024 + j]);
        size_t n = (size_t)b * 20480 + (size_t)qf * 4096 +
                   (vertical ? (pos * 64 + lw) : (lw * 64 + pos));
        ao[n * 256 + coff + head * 16 + d] = f2bf(acc);
    }
}

// ---------------- LN2: y bf16 (N,256) -> tn bf16 (N,256), one wave per token ----------------
__global__ __launch_bounds__(256) void ln2_kernel(const unsigned short* __restrict__ y,
                                                  const float* __restrict__ g,
                                                  const float* __restrict__ bta,
                                                  unsigned short* __restrict__ tn) {
    int tid = threadIdx.x;
    int lane = tid & 63, wvid = tid >> 6;
    int token = blockIdx.x * 4 + wvid;
    const unsigned short* yp = y + (size_t)token * 256;
    float v[4];
    #pragma unroll
    for (int e = 0; e < 4; ++e) v[e] = bf2f(yp[lane * 4 + e]);
    float s = v[0] + v[1] + v[2] + v[3];
    float sq = v[0] * v[0] + v[1] * v[1] + v[2] * v[2] + v[3] * v[3];
    for (int off = 32; off; off >>= 1) { s += __shfl_xor(s, off); sq += __shfl_xor(sq, off); }
    float mean = s * (1.f / 256.f);
    float var = sq * (1.f / 256.f) - mean * mean;
    float rstd = rsqrtf(var + 1e-5f);
    unsigned short* tp = tn + (size_t)token * 256;
    #pragma unroll
    for (int e = 0; e < 4; ++e) {
        int c = lane * 4 + e;
        tp[c] = f2bf((v[e] - mean) * rstd * g[c] + bta[c]);
    }
}

extern "C" void kernel_launch(void* const* d_in, const int* in_sizes, int n_in,
                              void* d_out, int out_size, void* d_ws, size_t ws_size,
                              hipStream_t stream) {
    (void)in_sizes; (void)n_in; (void)out_size; (void)ws_size;
    const float* x    = (const float*)d_in[0];
    const float* ln1g = (const float*)d_in[1];
    const float* ln1b = (const float*)d_in[2];
    const float* wh   = (const float*)d_in[3];
    const float* bh   = (const float*)d_in[4];
    const float* wv   = (const float*)d_in[5];
    const float* bv   = (const float*)d_in[6];
    const float* wf   = (const float*)d_in[7];
    const float* bfp  = (const float*)d_in[8];
    const float* ln2g = (const float*)d_in[9];
    const float* ln2b = (const float*)d_in[10];
    const float* w1   = (const float*)d_in[11];
    const float* b1   = (const float*)d_in[12];
    const float* w2   = (const float*)d_in[13];
    const float* b2   = (const float*)d_in[14];
    float* out = (float*)d_out;
    char* ws = (char*)d_ws;

    // workspace layout (total ~148.4 MB), no trailing backslashes in comments!
    unsigned short* whb = (unsigned short*)(ws + 0);
    unsigned short* wvb = (unsigned short*)(ws + 98304);
    unsigned short* wfb = (unsigned short*)(ws + 196608);
    unsigned short* w1b = (unsigned short*)(ws + 327680);
    unsigned short* w2b = (unsigned short*)(ws + 851968);
    const size_t off = 1572864;
    unsigned short* xn   = (unsigned short*)(ws + off);                    // 21.0 MB (reused as tn)
    unsigned short* xt   = (unsigned short*)(ws + off + 20971520ull);      // 21.0 MB
    unsigned short* qkvh = (unsigned short*)(ws + off + 41943040ull);      // 31.5 MB (hid part 1)
    unsigned short* qkvv = (unsigned short*)(ws + off + 73400320ull);      // 31.5 MB (hid part 2)
    unsigned short* ao   = (unsigned short*)(ws + off + 104857600ull);     // 21.0 MB (hid part 3)
    unsigned short* yb   = (unsigned short*)(ws + off + 125829120ull);     // 21.0 MB
    unsigned short* tnb  = xn;
    unsigned short* hid  = qkvh;   // hid (N x 1024, 84 MB) overlays qkvh/qkvv/ao (dead by FFN1)

    cvt_kernel<<<192,  256, 0, stream>>>(wh, whb, 49152);
    cvt_kernel<<<192,  256, 0, stream>>>(wv, wvb, 49152);
    cvt_kernel<<<256,  256, 0, stream>>>(wf, wfb, 65536);
    cvt_kernel<<<1024, 256, 0, stream>>>(w1, w1b, 262144);
    cvt_kernel<<<1024, 256, 0, stream>>>(w2, w2b, 262144);

    ln1_kernel<<<640, 256, 0, stream>>>(x, ln1g, ln1b, xn, xt);

    // QKV projections: (N x 128) @ (384 x 128)^T
    gemm_kernel<<<dim3(6, 640), 256, 0, stream>>>(xn,       256, whb, bh, qkvh, 384, nullptr, nullptr, 128, 0);
    gemm_kernel<<<dim3(6, 640), 256, 0, stream>>>(xn + 128, 256, wvb, bv, qkvv, 384, nullptr, nullptr, 128, 0);

    attn_kernel<<<1024, 256, 0, stream>>>(qkvh, ao, 0);
    attn_kernel<<<1024, 256, 0, stream>>>(qkvv, ao, 1);

    // proj + residual: y = ao @ wf^T + bf + x
    gemm_kernel<<<dim3(4, 640), 256, 0, stream>>>(ao, 256, wfb, bfp, yb, 256, xt, nullptr, 256, 1);

    ln2_kernel<<<10240, 256, 0, stream>>>(yb, ln2g, ln2b, tnb);

    // FFN1: hid = gelu(tn @ w1^T + b1)
    gemm_kernel<<<dim3(16, 640), 256, 0, stream>>>(tnb, 256, w1b, b1, hid, 1024, nullptr, nullptr, 256, 2);
    // FFN2 + residual + transpose: out = (y + hid @ w2^T + b2) -> (B,F,C,H,W) fp32
    gemm_kernel<<<dim3(4, 640), 256, 0, stream>>>(hid, 1024, w2b, b2, nullptr, 256, yb, out, 1024, 3);
}

// Round 3
// 358.860 us; speedup vs baseline: 1.0785x; 1.0785x over previous
//
#include <hip/hip_runtime.h>
#include <cstdint>
#include <cmath>

// Problem constants: B=2, F=5, C=256, H=64, W=64, HN=8, hd=16
// Token layout: n = (b*5+f)*4096 + h*64 + w, N = 40960 tokens, channels-last.

typedef __bf16 bf16x8 __attribute__((ext_vector_type(8)));
typedef float f32x4 __attribute__((ext_vector_type(4)));

__device__ __forceinline__ unsigned short f2bf(float f) {
    union { float f; unsigned int u; } v; v.f = f;
    unsigned int r = (v.u + 0x7fffu + ((v.u >> 16) & 1u)) >> 16;
    return (unsigned short)r;
}
__device__ __forceinline__ float bf2f(unsigned short h) {
    union { unsigned int u; float f; } v; v.u = ((unsigned int)h) << 16;
    return v.f;
}

// async global->LDS, 16B per lane; LDS dest = wave-uniform base + lane*16
__device__ __forceinline__ void gld16(const unsigned short* g, unsigned short* l) {
    __builtin_amdgcn_global_load_lds(
        (const __attribute__((address_space(1))) void*)g,
        (__attribute__((address_space(3))) void*)l, 16, 0, 0);
}

// ---------------- fused weight fp32 -> bf16 (all 5 weights, one launch) ----------------
__global__ __launch_bounds__(256) void cvt_all_kernel(
        const float* __restrict__ wh, const float* __restrict__ wv,
        const float* __restrict__ wf, const float* __restrict__ w1,
        const float* __restrict__ w2,
        unsigned short* __restrict__ whb, unsigned short* __restrict__ wvb,
        unsigned short* __restrict__ wfb, unsigned short* __restrict__ w1b,
        unsigned short* __restrict__ w2b) {
    int i = blockIdx.x * 256 + threadIdx.x;   // grid covers 688128 exactly
    const float* s; unsigned short* d; int j;
    if (i < 49152)       { s = wh; d = whb; j = i; }
    else if (i < 98304)  { s = wv; d = wvb; j = i - 49152; }
    else if (i < 163840) { s = wf; d = wfb; j = i - 98304; }
    else if (i < 425984) { s = w1; d = w1b; j = i - 163840; }
    else                 { s = w2; d = w2b; j = i - 425984; }
    d[j] = f2bf(s[j]);
}

// ---------------- LN1: x (B,F,C,H,W) fp32 -> xn bf16 (N,256) + xt bf16 (N,256) ----------------
__global__ __launch_bounds__(256) void ln1_kernel(const float* __restrict__ x,
                                                  const float* __restrict__ g,
                                                  const float* __restrict__ bta,
                                                  unsigned short* __restrict__ xn,
                                                  unsigned short* __restrict__ xt) {
    __shared__ unsigned short tile[64 * 257];   // [w][c], padded stride
    __shared__ float psum[4][64], psq[4][64], meanL[64], rstdL[64];
    int bx = blockIdx.x;
    int bf = bx >> 6, h = bx & 63;              // bf = b*5+f
    size_t base = (size_t)bf * 1048576 + (size_t)h * 64;
    int tid = threadIdx.x;
    int w = tid & 63, cg = tid >> 6;
    float s = 0.f, sq = 0.f;
    for (int k = 0; k < 64; ++k) {
        int c = cg * 64 + k;
        float v = x[base + (size_t)c * 4096 + w];   // lanes vary w -> coalesced
        s += v; sq += v * v;
        tile[w * 257 + c] = f2bf(v);
    }
    psum[cg][w] = s; psq[cg][w] = sq;
    __syncthreads();
    if (tid < 64) {
        float ss = psum[0][tid] + psum[1][tid] + psum[2][tid] + psum[3][tid];
        float qq = psq[0][tid] + psq[1][tid] + psq[2][tid] + psq[3][tid];
        float mean = ss * (1.f / 256.f);
        float var = qq * (1.f / 256.f) - mean * mean;
        meanL[tid] = mean;
        rstdL[tid] = rsqrtf(var + 1e-5f);
    }
    __syncthreads();
    int n0 = bf * 4096 + h * 64;
    float gc = g[tid], bc = bta[tid];           // tid == channel in pass 2
    for (int rep = 0; rep < 64; ++rep) {
        unsigned short raw = tile[rep * 257 + tid];
        float v = bf2f(raw);
        float o = (v - meanL[rep]) * rstdL[rep] * gc + bc;
        size_t oi = (size_t)(n0 + rep) * 256 + tid;   // coalesced
        xn[oi] = f2bf(o);
        xt[oi] = raw;
    }
}

// ---------------- 128x128 MFMA GEMM: C(MxN) = A(MxK) * B(NxK)^T (+epilogue) ----------------
// BK=64, 4 waves, each wave 64x64 (4x4 of 16x16x32), global_load_lds staging,
// XOR k-seg swizzle (seg ^ row&7) applied on the GLOBAL side of the async copy.
// modes: 0 = bias, store bf16
//        1 = bias + res(bf16, ldc), store bf16         (attn proj + x residual)
//        2 = bias + exact GELU, store bf16             (FFN1)
//        3 = bias + res(bf16,256), store fp32 transposed to (B,F,C,H,W) via LDS (FFN2)
__global__ __launch_bounds__(256) void gemm128_kernel(
        const unsigned short* __restrict__ A, int lda,
        const unsigned short* __restrict__ B,
        const float* __restrict__ bias,
        unsigned short* __restrict__ C, int ldc,
        const unsigned short* __restrict__ res,
        float* __restrict__ outT,
        int K, int mode) {
    __shared__ __align__(16) unsigned char smem[33792];   // As 16KB | Bs 16KB ; mode3: fp32 transpose buf
    unsigned short* As = (unsigned short*)smem;
    unsigned short* Bs = (unsigned short*)(smem + 16384);

    int tid = threadIdx.x;
    int lane = tid & 63, wvid = tid >> 6;
    int wm = wvid >> 1, wn = wvid & 1;          // wave covers rows wm*64.., cols wn*64..
    int r16 = lane & 15, kg = lane >> 4;

    // XCD-aware remap: L%8 -> xcd gets contiguous m-range, n-tile fastest within
    int nx = gridDim.x;
    int L = blockIdx.y * nx + blockIdx.x;
    int T = nx * gridDim.y;
    int newL = (T & 7) ? L : ((L & 7) * (T >> 3) + (L >> 3));
    int nt = newL % nx, mt = newL / nx;
    int m0 = mt * 128, n0 = nt * 128;

    // staging: wave w, issue i covers rows (i*4+w)*8 .. +8, 8x16B segs per row
    int srow = wvid * 8 + (lane >> 3);          // + i*32 per issue
    int segg = (lane & 7) ^ (lane >> 3);        // swizzled global k-seg (row&7 == lane>>3)
    const unsigned short* pA = A + (size_t)(m0 + srow) * lda + segg * 8;
    const unsigned short* pB = B + (size_t)(n0 + srow) * K + segg * 8;
    unsigned short* lA = As + wvid * 512;       // wave-uniform LDS bases
    unsigned short* lB = Bs + wvid * 512;

    f32x4 acc[4][4] = {};
    for (int k0 = 0; k0 < K; k0 += 64) {
        #pragma unroll
        for (int i = 0; i < 4; ++i) {
            gld16(pA + (size_t)i * 32 * lda, lA + i * 2048);
            gld16(pB + (size_t)i * 32 * K,  lB + i * 2048);
        }
        pA += 64; pB += 64;
        __syncthreads();
        #pragma unroll
        for (int t = 0; t < 2; ++t) {
            bf16x8 af[4], bfr[4];
            int ss = ((t * 4 + kg) ^ (r16 & 7)) * 8;   // un-swizzle on read
            #pragma unroll
            for (int i = 0; i < 4; ++i) {
                af[i]  = *(const bf16x8*)&As[(wm * 64 + i * 16 + r16) * 64 + ss];
                bfr[i] = *(const bf16x8*)&Bs[(wn * 64 + i * 16 + r16) * 64 + ss];
            }
            #pragma unroll
            for (int i = 0; i < 4; ++i)
                #pragma unroll
                for (int j = 0; j < 4; ++j)
                    acc[i][j] = __builtin_amdgcn_mfma_f32_16x16x32_bf16(af[i], bfr[j], acc[i][j], 0, 0, 0);
        }
        __syncthreads();
    }

    int rowBase = kg * 4;   // C/D: col = lane&15, row = (lane>>4)*4 + r
    if (mode == 3) {
        float* fl = (float*)smem;               // [128 tokens][66] fp32
        int bfi = m0 >> 12;
        int hbase = (m0 >> 6) & 63;             // block spans h = hbase, hbase+1
        for (int p = 0; p < 2; ++p) {
            __syncthreads();
            if (wn == p) {
                #pragma unroll
                for (int i = 0; i < 4; ++i)
                    #pragma unroll
                    for (int j = 0; j < 4; ++j)
                        #pragma unroll
                        for (int r = 0; r < 4; ++r) {
                            int ml = wm * 64 + i * 16 + rowBase + r;
                            int n = n0 + p * 64 + j * 16 + r16;
                            float v = acc[i][j][r] + bias[n] + bf2f(res[(size_t)(m0 + ml) * 256 + n]);
                            fl[ml * 66 + j * 16 + r16] = v;
                        }
            }
            __syncthreads();
            for (int r = tid >> 6; r < 128; r += 4) {      // 128 runs of 64 contiguous floats
                int nl = r & 63, tl2 = r >> 6;
                outT[(size_t)bfi * 1048576 + (size_t)(n0 + p * 64 + nl) * 4096 +
                     (size_t)(hbase + tl2) * 64 + lane] = fl[(tl2 * 64 + lane) * 66 + nl];
            }
        }
        return;
    }
    #pragma unroll
    for (int i = 0; i < 4; ++i)
        #pragma unroll
        for (int j = 0; j < 4; ++j)
            #pragma unroll
            for (int r = 0; r < 4; ++r) {
                int m = m0 + wm * 64 + i * 16 + rowBase + r;
                int n = n0 + wn * 64 + j * 16 + r16;
                float v = acc[i][j][r] + bias[n];
                if (mode == 1) v += bf2f(res[(size_t)m * ldc + n]);
                else if (mode == 2) v = 0.5f * v * (1.0f + erff(v * 0.70710678118f));
                C[(size_t)m * ldc + n] = f2bf(v);
            }
}

// ---------------- attention: per (b, head, line) group; seq F=5, feat 1024 ----------------
__global__ __launch_bounds__(256) void attn_kernel(const unsigned short* __restrict__ qkv,
                                                   unsigned short* __restrict__ ao,
                                                   int vertical) {
    __shared__ unsigned short qL[5 * 1024], kL[5 * 1024], vL[5 * 1024];
    __shared__ float sL[25];
    int g = blockIdx.x;
    int lw = g & 63;            // h (horizontal) or w (vertical)
    int head = (g >> 6) & 7;
    int b = g >> 9;
    int tid = threadIdx.x;
    for (int idx = tid; idx < 5120; idx += 256) {
        int f = idx >> 10, j = idx & 1023;
        int pos = j >> 4, d = j & 15;
        size_t n = (size_t)b * 20480 + (size_t)f * 4096 +
                   (vertical ? (pos * 64 + lw) : (lw * 64 + pos));
        size_t src = n * 384 + head * 16 + d;
        qL[idx] = qkv[src];
        kL[idx] = qkv[src + 128];
        vL[idx] = qkv[src + 256];
    }
    __syncthreads();
    int lane = tid & 63, wwv = tid >> 6;
    for (int p = wwv; p < 25; p += 4) {
        int qf = p / 5, kf = p - qf * 5;
        float acc = 0.f;
        const unsigned short* qp = &qL[qf * 1024 + lane * 16];
        const unsigned short* kp = &kL[kf * 1024 + lane * 16];
        #pragma unroll
        for (int t = 0; t < 16; ++t) acc += bf2f(qp[t]) * bf2f(kp[t]);
        for (int off = 32; off; off >>= 1) acc += __shfl_down(acc, off);
        if (lane == 0) sL[p] = acc * 0.03125f;   // 1/sqrt(1024)
    }
    __syncthreads();
    if (tid < 5) {
        float mx = -1e30f;
        for (int kf = 0; kf < 5; ++kf) mx = fmaxf(mx, sL[tid * 5 + kf]);
        float e[5], sum = 0.f;
        for (int kf = 0; kf < 5; ++kf) { e[kf] = expf(sL[tid * 5 + kf] - mx); sum += e[kf]; }
        float inv = 1.f / sum;
        for (int kf = 0; kf < 5; ++kf) sL[tid * 5 + kf] = e[kf] * inv;
    }
    __syncthreads();
    int coff = vertical ? 128 : 0;
    for (int idx = tid; idx < 5120; idx += 256) {
        int qf = idx >> 10, j = idx & 1023;
        int pos = j >> 4, d = j & 15;
        float acc = 0.f;
        #pragma unroll
        for (int kf = 0; kf < 5; ++kf) acc += sL[qf * 5 + kf] * bf2f(vL[kf * 1024 + j]);
        size_t n = (size_t)b * 20480 + (size_t)qf * 4096 +
                   (vertical ? (pos * 64 + lw) : (lw * 64 + pos));
        ao[n * 256 + coff + head * 16 + d] = f2bf(acc);
    }
}

// ---------------- LN2: y bf16 (N,256) -> tn bf16 (N,256), one wave per token ----------------
__global__ __launch_bounds__(256) void ln2_kernel(const unsigned short* __restrict__ y,
                                                  const float* __restrict__ g,
                                                  const float* __restrict__ bta,
                                                  unsigned short* __restrict__ tn) {
    int tid = threadIdx.x;
    int lane = tid & 63, wvid = tid >> 6;
    int token = blockIdx.x * 4 + wvid;
    const unsigned short* yp = y + (size_t)token * 256;
    float v[4];
    #pragma unroll
    for (int e = 0; e < 4; ++e) v[e] = bf2f(yp[lane * 4 + e]);
    float s = v[0] + v[1] + v[2] + v[3];
    float sq = v[0] * v[0] + v[1] * v[1] + v[2] * v[2] + v[3] * v[3];
    for (int off = 32; off; off >>= 1) { s += __shfl_xor(s, off); sq += __shfl_xor(sq, off); }
    float mean = s * (1.f / 256.f);
    float var = sq * (1.f / 256.f) - mean * mean;
    float rstd = rsqrtf(var + 1e-5f);
    unsigned short* tp = tn + (size_t)token * 256;
    #pragma unroll
    for (int e = 0; e < 4; ++e) {
        int c = lane * 4 + e;
        tp[c] = f2bf((v[e] - mean) * rstd * g[c] + bta[c]);
    }
}

extern "C" void kernel_launch(void* const* d_in, const int* in_sizes, int n_in,
                              void* d_out, int out_size, void* d_ws, size_t ws_size,
                              hipStream_t stream) {
    (void)in_sizes; (void)n_in; (void)out_size; (void)ws_size;
    const float* x    = (const float*)d_in[0];
    const float* ln1g = (const float*)d_in[1];
    const float* ln1b = (const float*)d_in[2];
    const float* wh   = (const float*)d_in[3];
    const float* bh   = (const float*)d_in[4];
    const float* wv   = (const float*)d_in[5];
    const float* bv   = (const float*)d_in[6];
    const float* wf   = (const float*)d_in[7];
    const float* bfp  = (const float*)d_in[8];
    const float* ln2g = (const float*)d_in[9];
    const float* ln2b = (const float*)d_in[10];
    const float* w1   = (const float*)d_in[11];
    const float* b1   = (const float*)d_in[12];
    const float* w2   = (const float*)d_in[13];
    const float* b2   = (const float*)d_in[14];
    float* out = (float*)d_out;
    char* ws = (char*)d_ws;

    // workspace layout (total ~148.4 MB)
    unsigned short* whb = (unsigned short*)(ws + 0);
    unsigned short* wvb = (unsigned short*)(ws + 98304);
    unsigned short* wfb = (unsigned short*)(ws + 196608);
    unsigned short* w1b = (unsigned short*)(ws + 327680);
    unsigned short* w2b = (unsigned short*)(ws + 851968);
    const size_t off = 1572864;
    unsigned short* xn   = (unsigned short*)(ws + off);                    // 21.0 MB (reused as tn)
    unsigned short* xt   = (unsigned short*)(ws + off + 20971520ull);      // 21.0 MB
    unsigned short* qkvh = (unsigned short*)(ws + off + 41943040ull);      // 31.5 MB (hid part 1)
    unsigned short* qkvv = (unsigned short*)(ws + off + 73400320ull);      // 31.5 MB (hid part 2)
    unsigned short* ao   = (unsigned short*)(ws + off + 104857600ull);     // 21.0 MB (hid part 3)
    unsigned short* yb   = (unsigned short*)(ws + off + 125829120ull);     // 21.0 MB
    unsigned short* tnb  = xn;
    unsigned short* hid  = qkvh;   // hid (N x 1024, 84 MB) overlays qkvh/qkvv/ao (dead by FFN1)

    cvt_all_kernel<<<2688, 256, 0, stream>>>(wh, wv, wf, w1, w2, whb, wvb, wfb, w1b, w2b);

    ln1_kernel<<<640, 256, 0, stream>>>(x, ln1g, ln1b, xn, xt);

    // QKV projections: (N x 128) @ (384 x 128)^T
    gemm128_kernel<<<dim3(3, 320), 256, 0, stream>>>(xn,       256, whb, bh, qkvh, 384, nullptr, nullptr, 128, 0);
    gemm128_kernel<<<dim3(3, 320), 256, 0, stream>>>(xn + 128, 256, wvb, bv, qkvv, 384, nullptr, nullptr, 128, 0);

    attn_kernel<<<1024, 256, 0, stream>>>(qkvh, ao, 0);
    attn_kernel<<<1024, 256, 0, stream>>>(qkvv, ao, 1);

    // proj + residual: y = ao @ wf^T + bf + x
    gemm128_kernel<<<dim3(2, 320), 256, 0, stream>>>(ao, 256, wfb, bfp, yb, 256, xt, nullptr, 256, 1);

    ln2_kernel<<<10240, 256, 0, stream>>>(yb, ln2g, ln2b, tnb);

    // FFN1: hid = gelu(tn @ w1^T + b1)
    gemm128_kernel<<<dim3(8, 320), 256, 0, stream>>>(tnb, 256, w1b, b1, hid, 1024, nullptr, nullptr, 256, 2);
    // FFN2 + residual + transpose: out = (y + hid @ w2^T + b2) -> (B,F,C,H,W) fp32
    gemm128_kernel<<<dim3(2, 320), 256, 0, stream>>>(hid, 1024, w2b, b2, nullptr, 256, yb, out, 1024, 3);
}

// Round 5
// 342.187 us; speedup vs baseline: 1.1311x; 1.0487x over previous
//
#include <hip/hip_runtime.h>
#include <cstdint>
#include <cmath>

// Problem constants: B=2, F=5, C=256, H=64, W=64, HN=8, hd=16
// Token layout: n = (b*5+f)*4096 + h*64 + w, N = 40960 tokens, channels-last.

typedef __bf16 bf16x8 __attribute__((ext_vector_type(8)));
typedef float f32x4 __attribute__((ext_vector_type(4)));

__device__ __forceinline__ unsigned short f2bf(float f) {
    union { float f; unsigned int u; } v; v.f = f;
    unsigned int r = (v.u + 0x7fffu + ((v.u >> 16) & 1u)) >> 16;
    return (unsigned short)r;
}
__device__ __forceinline__ float bf2f(unsigned short h) {
    union { unsigned int u; float f; } v; v.u = ((unsigned int)h) << 16;
    return v.f;
}
// tanh-form GELU, fully inline: x*sigmoid(2z), z = x*(c0 + c1*x^2)
// max |diff vs exact erf-GELU| ~2e-4, far below bf16 quantization.
__device__ __forceinline__ float gelu_fast(float x) {
    float z2 = 2.8853900817779268f * x * (0.7978845608028654f + 0.0356774081363001f * x * x);
    float u = __builtin_amdgcn_exp2f(z2);       // v_exp_f32
    return x - x * __builtin_amdgcn_rcpf(1.0f + u);
}

// async global->LDS, 16B per lane; LDS dest = wave-uniform base + lane*16
__device__ __forceinline__ void gld16(const unsigned short* g, unsigned short* l) {
    __builtin_amdgcn_global_load_lds(
        (const __attribute__((address_space(1))) void*)g,
        (__attribute__((address_space(3))) void*)l, 16, 0, 0);
}

// ---------------- fused weight fp32 -> bf16 (all 5 weights, one launch) ----------------
__global__ __launch_bounds__(256) void cvt_all_kernel(
        const float* __restrict__ wh, const float* __restrict__ wv,
        const float* __restrict__ wf, const float* __restrict__ w1,
        const float* __restrict__ w2,
        unsigned short* __restrict__ whb, unsigned short* __restrict__ wvb,
        unsigned short* __restrict__ wfb, unsigned short* __restrict__ w1b,
        unsigned short* __restrict__ w2b) {
    int i = blockIdx.x * 256 + threadIdx.x;   // grid covers 688128 exactly
    const float* s; unsigned short* d; int j;
    if (i < 49152)       { s = wh; d = whb; j = i; }
    else if (i < 98304)  { s = wv; d = wvb; j = i - 49152; }
    else if (i < 163840) { s = wf; d = wfb; j = i - 98304; }
    else if (i < 425984) { s = w1; d = w1b; j = i - 163840; }
    else                 { s = w2; d = w2b; j = i - 425984; }
    d[j] = f2bf(s[j]);
}

// ---------------- LN1: x (B,F,C,H,W) fp32 -> xn bf16 (N,256) + xt bf16 (N,256) ----------------
__global__ __launch_bounds__(256) void ln1_kernel(const float* __restrict__ x,
                                                  const float* __restrict__ g,
                                                  const float* __restrict__ bta,
                                                  unsigned short* __restrict__ xn,
                                                  unsigned short* __restrict__ xt) {
    __shared__ unsigned short tile[64 * 257];   // [w][c], padded stride
    __shared__ float psum[4][64], psq[4][64], meanL[64], rstdL[64];
    int bx = blockIdx.x;
    int bf = bx >> 6, h = bx & 63;              // bf = b*5+f
    size_t base = (size_t)bf * 1048576 + (size_t)h * 64;
    int tid = threadIdx.x;
    int w = tid & 63, cg = tid >> 6;
    float s = 0.f, sq = 0.f;
    for (int k = 0; k < 64; ++k) {
        int c = cg * 64 + k;
        float v = x[base + (size_t)c * 4096 + w];   // lanes vary w -> coalesced
        s += v; sq += v * v;
        tile[w * 257 + c] = f2bf(v);
    }
    psum[cg][w] = s; psq[cg][w] = sq;
    __syncthreads();
    if (tid < 64) {
        float ss = psum[0][tid] + psum[1][tid] + psum[2][tid] + psum[3][tid];
        float qq = psq[0][tid] + psq[1][tid] + psq[2][tid] + psq[3][tid];
        float mean = ss * (1.f / 256.f);
        float var = qq * (1.f / 256.f) - mean * mean;
        meanL[tid] = mean;
        rstdL[tid] = rsqrtf(var + 1e-5f);
    }
    __syncthreads();
    int n0 = bf * 4096 + h * 64;
    float gc = g[tid], bc = bta[tid];           // tid == channel in pass 2
    for (int rep = 0; rep < 64; ++rep) {
        unsigned short raw = tile[rep * 257 + tid];
        float v = bf2f(raw);
        float o = (v - meanL[rep]) * rstdL[rep] * gc + bc;
        size_t oi = (size_t)(n0 + rep) * 256 + tid;   // coalesced
        xn[oi] = f2bf(o);
        xt[oi] = raw;
    }
}

// ---------------- 128x128 MFMA GEMM: C(MxN) = A(MxK) * B(NxK)^T (+epilogue) ----------------
// BK=64, 4 waves, each wave 64x64 (4x4 of 16x16x32), global_load_lds staging,
// XOR k-seg swizzle (seg ^ row&7) applied on the GLOBAL side of the async copy.
// modes: 0 = bias, store bf16
//        1 = bias + res(bf16, ldc), store bf16         (attn proj + x residual)
//        2 = bias + fast GELU, store bf16              (FFN1)
//        3 = bias + res(bf16,256), store fp32 transposed to (B,F,C,H,W) via LDS (FFN2)
__global__ __launch_bounds__(256) void gemm128_kernel(
        const unsigned short* __restrict__ A, int lda,
        const unsigned short* __restrict__ B,
        const float* __restrict__ bias,
        unsigned short* __restrict__ C, int ldc,
        const unsigned short* __restrict__ res,
        float* __restrict__ outT,
        int K, int mode) {
    __shared__ __align__(16) unsigned char smem[32768];   // As 16KB | Bs 16KB ; mode3: fp32 [128][64] swizzled
    unsigned short* As = (unsigned short*)smem;
    unsigned short* Bs = (unsigned short*)(smem + 16384);

    int tid = threadIdx.x;
    int lane = tid & 63, wvid = tid >> 6;
    int wm = wvid >> 1, wn = wvid & 1;          // wave covers rows wm*64.., cols wn*64..
    int r16 = lane & 15, kg = lane >> 4;

    // XCD-aware remap: L%8 -> xcd gets contiguous m-range, n-tile fastest within
    int nx = gridDim.x;
    int L = blockIdx.y * nx + blockIdx.x;
    int T = nx * gridDim.y;
    int newL = (T & 7) ? L : ((L & 7) * (T >> 3) + (L >> 3));
    int nt = newL % nx, mt = newL / nx;
    int m0 = mt * 128, n0 = nt * 128;

    // staging: wave w, issue i covers rows (i*4+w)*8 .. +8, 8x16B segs per row
    int srow = wvid * 8 + (lane >> 3);          // + i*32 per issue
    int segg = (lane & 7) ^ (lane >> 3);        // swizzled global k-seg (row&7 == lane>>3)
    const unsigned short* pA = A + (size_t)(m0 + srow) * lda + segg * 8;
    const unsigned short* pB = B + (size_t)(n0 + srow) * K + segg * 8;
    unsigned short* lA = As + wvid * 512;       // wave-uniform LDS bases
    unsigned short* lB = Bs + wvid * 512;

    f32x4 acc[4][4] = {};
    for (int k0 = 0; k0 < K; k0 += 64) {
        #pragma unroll
        for (int i = 0; i < 4; ++i) {
            gld16(pA + (size_t)i * 32 * lda, lA + i * 2048);
            gld16(pB + (size_t)i * 32 * K,  lB + i * 2048);
        }
        pA += 64; pB += 64;
        __syncthreads();
        #pragma unroll
        for (int t = 0; t < 2; ++t) {
            bf16x8 af[4], bfr[4];
            int ss = ((t * 4 + kg) ^ (r16 & 7)) * 8;   // un-swizzle on read
            #pragma unroll
            for (int i = 0; i < 4; ++i) {
                af[i]  = *(const bf16x8*)&As[(wm * 64 + i * 16 + r16) * 64 + ss];
                bfr[i] = *(const bf16x8*)&Bs[(wn * 64 + i * 16 + r16) * 64 + ss];
            }
            #pragma unroll
            for (int i = 0; i < 4; ++i)
                #pragma unroll
                for (int j = 0; j < 4; ++j)
                    acc[i][j] = __builtin_amdgcn_mfma_f32_16x16x32_bf16(af[i], bfr[j], acc[i][j], 0, 0, 0);
        }
        __syncthreads();
    }

    int rowBase = kg * 4;   // C/D: col = lane&15, row = (lane>>4)*4 + r
    if (mode == 3) {
        float* fl = (float*)smem;               // [128 tokens][64] fp32, XOR col swizzle
        int bfi = m0 >> 12;
        int hbase = (m0 >> 6) & 63;             // block spans h = hbase, hbase+1
        for (int p = 0; p < 2; ++p) {
            __syncthreads();
            if (wn == p) {
                #pragma unroll
                for (int i = 0; i < 4; ++i)
                    #pragma unroll
                    for (int j = 0; j < 4; ++j)
                        #pragma unroll
                        for (int r = 0; r < 4; ++r) {
                            int ml = wm * 64 + i * 16 + rowBase + r;
                            int nl = j * 16 + r16;
                            int n = n0 + p * 64 + nl;
                            float v = acc[i][j][r] + bias[n] + bf2f(res[(size_t)(m0 + ml) * 256 + n]);
                            fl[ml * 64 + (nl ^ (ml & 63))] = v;
                        }
            }
            __syncthreads();
            for (int r = tid >> 6; r < 128; r += 4) {      // 128 runs of 64 contiguous floats
                int nl = r & 63, tl2 = r >> 6;
                int token = tl2 * 64 + lane;
                outT[(size_t)bfi * 1048576 + (size_t)(n0 + p * 64 + nl) * 4096 +
                     (size_t)(hbase + tl2) * 64 + lane] = fl[token * 64 + (nl ^ (token & 63))];
            }
        }
        return;
    }
    #pragma unroll
    for (int i = 0; i < 4; ++i)
        #pragma unroll
        for (int j = 0; j < 4; ++j)
            #pragma unroll
            for (int r = 0; r < 4; ++r) {
                int m = m0 + wm * 64 + i * 16 + rowBase + r;
                int n = n0 + wn * 64 + j * 16 + r16;
                float v = acc[i][j][r] + bias[n];
                if (mode == 1) v += bf2f(res[(size_t)m * ldc + n]);
                else if (mode == 2) v = gelu_fast(v);
                C[(size_t)m * ldc + n] = f2bf(v);
            }
}

// ---------------- attention (both directions, one launch): per (dir, b, head, line) ----------------
__global__ __launch_bounds__(256) void attn_kernel(const unsigned short* __restrict__ qkvH,
                                                   const unsigned short* __restrict__ qkvV,
                                                   unsigned short* __restrict__ ao) {
    __shared__ unsigned short qL[5 * 1024], kL[5 * 1024], vL[5 * 1024];
    __shared__ float sL[25];
    int g = blockIdx.x;
    int vertical = g >> 10;
    const unsigned short* qkv = vertical ? qkvV : qkvH;
    int lw = g & 63;            // h (horizontal) or w (vertical)
    int head = (g >> 6) & 7;
    int b = (g >> 9) & 1;
    int tid = threadIdx.x;
    for (int idx = tid; idx < 5120; idx += 256) {
        int f = idx >> 10, j = idx & 1023;
        int pos = j >> 4, d = j & 15;
        size_t n = (size_t)b * 20480 + (size_t)f * 4096 +
                   (vertical ? (pos * 64 + lw) : (lw * 64 + pos));
        size_t src = n * 384 + head * 16 + d;
        qL[idx] = qkv[src];
        kL[idx] = qkv[src + 128];
        vL[idx] = qkv[src + 256];
    }
    __syncthreads();
    int lane = tid & 63, wwv = tid >> 6;
    for (int p = wwv; p < 25; p += 4) {
        int qf = p / 5, kf = p - qf * 5;
        float acc = 0.f;
        const unsigned short* qp = &qL[qf * 1024 + lane * 16];
        const unsigned short* kp = &kL[kf * 1024 + lane * 16];
        #pragma unroll
        for (int t = 0; t < 16; ++t) acc += bf2f(qp[t]) * bf2f(kp[t]);
        for (int off = 32; off; off >>= 1) acc += __shfl_down(acc, off);
        if (lane == 0) sL[p] = acc * 0.03125f;   // 1/sqrt(1024)
    }
    __syncthreads();
    if (tid < 5) {
        float mx = -1e30f;
        for (int kf = 0; kf < 5; ++kf) mx = fmaxf(mx, sL[tid * 5 + kf]);
        float e[5], sum = 0.f;
        for (int kf = 0; kf < 5; ++kf) { e[kf] = expf(sL[tid * 5 + kf] - mx); sum += e[kf]; }
        float inv = 1.f / sum;
        for (int kf = 0; kf < 5; ++kf) sL[tid * 5 + kf] = e[kf] * inv;
    }
    __syncthreads();
    int coff = vertical ? 128 : 0;
    for (int idx = tid; idx < 5120; idx += 256) {
        int qf = idx >> 10, j = idx & 1023;
        int pos = j >> 4, d = j & 15;
        float acc = 0.f;
        #pragma unroll
        for (int kf = 0; kf < 5; ++kf) acc += sL[qf * 5 + kf] * bf2f(vL[kf * 1024 + j]);
        size_t n = (size_t)b * 20480 + (size_t)qf * 4096 +
                   (vertical ? (pos * 64 + lw) : (lw * 64 + pos));
        ao[n * 256 + coff + head * 16 + d] = f2bf(acc);
    }
}

// ---------------- LN2: y bf16 (N,256) -> tn bf16 (N,256), one wave per token ----------------
__global__ __launch_bounds__(256) void ln2_kernel(const unsigned short* __restrict__ y,
                                                  const float* __restrict__ g,
                                                  const float* __restrict__ bta,
                                                  unsigned short* __restrict__ tn) {
    int tid = threadIdx.x;
    int lane = tid & 63, wvid = tid >> 6;
    int token = blockIdx.x * 4 + wvid;
    const unsigned short* yp = y + (size_t)token * 256;
    float v[4];
    #pragma unroll
    for (int e = 0; e < 4; ++e) v[e] = bf2f(yp[lane * 4 + e]);
    float s = v[0] + v[1] + v[2] + v[3];
    float sq = v[0] * v[0] + v[1] * v[1] + v[2] * v[2] + v[3] * v[3];
    for (int off = 32; off; off >>= 1) { s += __shfl_xor(s, off); sq += __shfl_xor(sq, off); }
    float mean = s * (1.f / 256.f);
    float var = sq * (1.f / 256.f) - mean * mean;
    float rstd = rsqrtf(var + 1e-5f);
    unsigned short* tp = tn + (size_t)token * 256;
    #pragma unroll
    for (int e = 0; e < 4; ++e) {
        int c = lane * 4 + e;
        tp[c] = f2bf((v[e] - mean) * rstd * g[c] + bta[c]);
    }
}

extern "C" void kernel_launch(void* const* d_in, const int* in_sizes, int n_in,
                              void* d_out, int out_size, void* d_ws, size_t ws_size,
                              hipStream_t stream) {
    (void)in_sizes; (void)n_in; (void)out_size; (void)ws_size;
    const float* x    = (const float*)d_in[0];
    const float* ln1g = (const float*)d_in[1];
    const float* ln1b = (const float*)d_in[2];
    const float* wh   = (const float*)d_in[3];
    const float* bh   = (const float*)d_in[4];
    const float* wv   = (const float*)d_in[5];
    const float* bv   = (const float*)d_in[6];
    const float* wf   = (const float*)d_in[7];
    const float* bfp  = (const float*)d_in[8];
    const float* ln2g = (const float*)d_in[9];
    const float* ln2b = (const float*)d_in[10];
    const float* w1   = (const float*)d_in[11];
    const float* b1   = (const float*)d_in[12];
    const float* w2   = (const float*)d_in[13];
    const float* b2   = (const float*)d_in[14];
    float* out = (float*)d_out;
    char* ws = (char*)d_ws;

    // workspace layout (total ~148.4 MB)
    unsigned short* whb = (unsigned short*)(ws + 0);
    unsigned short* wvb = (unsigned short*)(ws + 98304);
    unsigned short* wfb = (unsigned short*)(ws + 196608);
    unsigned short* w1b = (unsigned short*)(ws + 327680);
    unsigned short* w2b = (unsigned short*)(ws + 851968);
    const size_t off = 1572864;
    unsigned short* xn   = (unsigned short*)(ws + off);                    // 21.0 MB (reused as tn)
    unsigned short* xt   = (unsigned short*)(ws + off + 20971520ull);      // 21.0 MB
    unsigned short* qkvh = (unsigned short*)(ws + off + 41943040ull);      // 31.5 MB (hid part 1)
    unsigned short* qkvv = (unsigned short*)(ws + off + 73400320ull);      // 31.5 MB (hid part 2)
    unsigned short* ao   = (unsigned short*)(ws + off + 104857600ull);     // 21.0 MB (hid part 3)
    unsigned short* yb   = (unsigned short*)(ws + off + 125829120ull);     // 21.0 MB
    unsigned short* tnb  = xn;
    unsigned short* hid  = qkvh;   // hid (N x 1024, 84 MB) overlays qkvh/qkvv/ao (dead by FFN1)

    cvt_all_kernel<<<2688, 256, 0, stream>>>(wh, wv, wf, w1, w2, whb, wvb, wfb, w1b, w2b);

    ln1_kernel<<<640, 256, 0, stream>>>(x, ln1g, ln1b, xn, xt);

    // QKV projections: (N x 128) @ (384 x 128)^T
    gemm128_kernel<<<dim3(3, 320), 256, 0, stream>>>(xn,       256, whb, bh, qkvh, 384, nullptr, nullptr, 128, 0);
    gemm128_kernel<<<dim3(3, 320), 256, 0, stream>>>(xn + 128, 256, wvb, bv, qkvv, 384, nullptr, nullptr, 128, 0);

    attn_kernel<<<2048, 256, 0, stream>>>(qkvh, qkvv, ao);

    // proj + residual: y = ao @ wf^T + bf + x
    gemm128_kernel<<<dim3(2, 320), 256, 0, stream>>>(ao, 256, wfb, bfp, yb, 256, xt, nullptr, 256, 1);

    ln2_kernel<<<10240, 256, 0, stream>>>(yb, ln2g, ln2b, tnb);

    // FFN1: hid = gelu(tn @ w1^T + b1)
    gemm128_kernel<<<dim3(8, 320), 256, 0, stream>>>(tnb, 256, w1b, b1, hid, 1024, nullptr, nullptr, 256, 2);
    // FFN2 + residual + transpose: out = (y + hid @ w2^T + b2) -> (B,F,C,H,W) fp32
    gemm128_kernel<<<dim3(2, 320), 256, 0, stream>>>(hid, 1024, w2b, b2, nullptr, 256, yb, out, 1024, 3);
}

// Round 6
// 340.574 us; speedup vs baseline: 1.1364x; 1.0047x over previous
//
#include <hip/hip_runtime.h>
#include <cstdint>
#include <cmath>

// Problem constants: B=2, F=5, C=256, H=64, W=64, HN=8, hd=16
// Token layout: n = (b*5+f)*4096 + h*64 + w, N = 40960 tokens, channels-last.

typedef __bf16 bf16x8 __attribute__((ext_vector_type(8)));
typedef float f32x4 __attribute__((ext_vector_type(4)));

__device__ __forceinline__ unsigned short f2bf(float f) {
    union { float f; unsigned int u; } v; v.f = f;
    unsigned int r = (v.u + 0x7fffu + ((v.u >> 16) & 1u)) >> 16;
    return (unsigned short)r;
}
__device__ __forceinline__ float bf2f(unsigned short h) {
    union { unsigned int u; float f; } v; v.u = ((unsigned int)h) << 16;
    return v.f;
}
// tanh-form GELU, fully inline: x*sigmoid(2z), z = x*(c0 + c1*x^2)
// max |diff vs exact erf-GELU| ~2e-4, far below bf16 quantization.
__device__ __forceinline__ float gelu_fast(float x) {
    float z2 = 2.8853900817779268f * x * (0.7978845608028654f + 0.0356774081363001f * x * x);
    float u = __builtin_amdgcn_exp2f(z2);       // v_exp_f32
    return x - x * __builtin_amdgcn_rcpf(1.0f + u);
}

// async global->LDS, 16B per lane; LDS dest = wave-uniform base + lane*16
__device__ __forceinline__ void gld16(const unsigned short* g, unsigned short* l) {
    __builtin_amdgcn_global_load_lds(
        (const __attribute__((address_space(1))) void*)g,
        (__attribute__((address_space(3))) void*)l, 16, 0, 0);
}

// ---------------- fused weight fp32 -> bf16 (all 5 weights, one launch) ----------------
__global__ __launch_bounds__(256) void cvt_all_kernel(
        const float* __restrict__ wh, const float* __restrict__ wv,
        const float* __restrict__ wf, const float* __restrict__ w1,
        const float* __restrict__ w2,
        unsigned short* __restrict__ whb, unsigned short* __restrict__ wvb,
        unsigned short* __restrict__ wfb, unsigned short* __restrict__ w1b,
        unsigned short* __restrict__ w2b) {
    int i = blockIdx.x * 256 + threadIdx.x;   // grid covers 688128 exactly
    const float* s; unsigned short* d; int j;
    if (i < 49152)       { s = wh; d = whb; j = i; }
    else if (i < 98304)  { s = wv; d = wvb; j = i - 49152; }
    else if (i < 163840) { s = wf; d = wfb; j = i - 98304; }
    else if (i < 425984) { s = w1; d = w1b; j = i - 163840; }
    else                 { s = w2; d = w2b; j = i - 425984; }
    d[j] = f2bf(s[j]);
}

// ---------------- LN1: x (B,F,C,H,W) fp32 -> xn bf16 (N,256) + xt bf16 (N,256) ----------------
__global__ __launch_bounds__(256) void ln1_kernel(const float* __restrict__ x,
                                                  const float* __restrict__ g,
                                                  const float* __restrict__ bta,
                                                  unsigned short* __restrict__ xn,
                                                  unsigned short* __restrict__ xt) {
    __shared__ unsigned short tile[64 * 257];   // [w][c], padded stride
    __shared__ float psum[4][64], psq[4][64], meanL[64], rstdL[64];
    int bx = blockIdx.x;
    int bf = bx >> 6, h = bx & 63;              // bf = b*5+f
    size_t base = (size_t)bf * 1048576 + (size_t)h * 64;
    int tid = threadIdx.x;
    int w = tid & 63, cg = tid >> 6;
    float s = 0.f, sq = 0.f;
    for (int k = 0; k < 64; ++k) {
        int c = cg * 64 + k;
        float v = x[base + (size_t)c * 4096 + w];   // lanes vary w -> coalesced
        s += v; sq += v * v;
        tile[w * 257 + c] = f2bf(v);
    }
    psum[cg][w] = s; psq[cg][w] = sq;
    __syncthreads();
    if (tid < 64) {
        float ss = psum[0][tid] + psum[1][tid] + psum[2][tid] + psum[3][tid];
        float qq = psq[0][tid] + psq[1][tid] + psq[2][tid] + psq[3][tid];
        float mean = ss * (1.f / 256.f);
        float var = qq * (1.f / 256.f) - mean * mean;
        meanL[tid] = mean;
        rstdL[tid] = rsqrtf(var + 1e-5f);
    }
    __syncthreads();
    int n0 = bf * 4096 + h * 64;
    float gc = g[tid], bc = bta[tid];           // tid == channel in pass 2
    for (int rep = 0; rep < 64; ++rep) {
        unsigned short raw = tile[rep * 257 + tid];
        float v = bf2f(raw);
        float o = (v - meanL[rep]) * rstdL[rep] * gc + bc;
        size_t oi = (size_t)(n0 + rep) * 256 + tid;   // coalesced
        xn[oi] = f2bf(o);
        xt[oi] = raw;
    }
}

// ---------------- 128x128 MFMA GEMM: C(MxN) = A(MxK) * B(NxK)^T (+epilogue) ----------------
// BK=64, 4 waves, each wave 64x64 (4x4 of 16x16x32), global_load_lds staging,
// XOR k-seg swizzle on the GLOBAL side of the async copy.
// Epilogue (modes 0/1/2): per-wave LDS repack -> global_store_dwordx4 (coalesced).
// modes: 0 = bias, store bf16
//        1 = bias + res(bf16, ldc), store bf16         (attn proj + x residual)
//        2 = bias + fast GELU, store bf16              (FFN1)
//        3 = bias + res(bf16,256), store fp32 transposed to (B,F,C,H,W) via LDS (FFN2)
__global__ __launch_bounds__(256) void gemm128_kernel(
        const unsigned short* __restrict__ A, int lda,
        const unsigned short* __restrict__ B,
        const float* __restrict__ bias,
        unsigned short* __restrict__ C, int ldc,
        const unsigned short* __restrict__ res,
        float* __restrict__ outT,
        int K, int mode) {
    __shared__ __align__(16) unsigned char smem[32768];   // As 16KB | Bs 16KB ; reused by epilogues
    unsigned short* As = (unsigned short*)smem;
    unsigned short* Bs = (unsigned short*)(smem + 16384);

    int tid = threadIdx.x;
    int lane = tid & 63, wvid = tid >> 6;
    int wm = wvid >> 1, wn = wvid & 1;          // wave covers rows wm*64.., cols wn*64..
    int r16 = lane & 15, kg = lane >> 4;

    // XCD-aware remap: L%8 -> xcd gets contiguous m-range, n-tile fastest within
    int nx = gridDim.x;
    int L = blockIdx.y * nx + blockIdx.x;
    int T = nx * gridDim.y;
    int newL = (T & 7) ? L : ((L & 7) * (T >> 3) + (L >> 3));
    int nt = newL % nx, mt = newL / nx;
    int m0 = mt * 128, n0 = nt * 128;

    // staging: wave w, issue i covers rows (i*4+w)*8 .. +8, 8x16B segs per row
    int srow = wvid * 8 + (lane >> 3);          // + i*32 per issue
    int segg = (lane & 7) ^ (lane >> 3);        // swizzled global k-seg (row&7 == lane>>3)
    const unsigned short* pA = A + (size_t)(m0 + srow) * lda + segg * 8;
    const unsigned short* pB = B + (size_t)(n0 + srow) * K + segg * 8;
    unsigned short* lA = As + wvid * 512;       // wave-uniform LDS bases
    unsigned short* lB = Bs + wvid * 512;

    f32x4 acc[4][4] = {};
    for (int k0 = 0; k0 < K; k0 += 64) {
        #pragma unroll
        for (int i = 0; i < 4; ++i) {
            gld16(pA + (size_t)i * 32 * lda, lA + i * 2048);
            gld16(pB + (size_t)i * 32 * K,  lB + i * 2048);
        }
        pA += 64; pB += 64;
        __syncthreads();
        #pragma unroll
        for (int t = 0; t < 2; ++t) {
            bf16x8 af[4], bfr[4];
            int ss = ((t * 4 + kg) ^ (r16 & 7)) * 8;   // un-swizzle on read
            #pragma unroll
            for (int i = 0; i < 4; ++i) {
                af[i]  = *(const bf16x8*)&As[(wm * 64 + i * 16 + r16) * 64 + ss];
                bfr[i] = *(const bf16x8*)&Bs[(wn * 64 + i * 16 + r16) * 64 + ss];
            }
            #pragma unroll
            for (int i = 0; i < 4; ++i)
                #pragma unroll
                for (int j = 0; j < 4; ++j)
                    acc[i][j] = __builtin_amdgcn_mfma_f32_16x16x32_bf16(af[i], bfr[j], acc[i][j], 0, 0, 0);
        }
        __syncthreads();
    }
    // After final barrier all waves are done with As/Bs -> smem reusable.

    if (mode == 3) {
        float* fl = (float*)smem;               // [128 tokens][64] fp32, XOR col swizzle
        int bfi = m0 >> 12;
        int hbase = (m0 >> 6) & 63;             // block spans h = hbase, hbase+1
        for (int p = 0; p < 2; ++p) {
            __syncthreads();
            if (wn == p) {
                #pragma unroll
                for (int i = 0; i < 4; ++i)
                    #pragma unroll
                    for (int j = 0; j < 4; ++j)
                        #pragma unroll
                        for (int r = 0; r < 4; ++r) {
                            int ml = wm * 64 + i * 16 + kg * 4 + r;
                            int nl = j * 16 + r16;
                            int n = n0 + p * 64 + nl;
                            float v = acc[i][j][r] + bias[n] + bf2f(res[(size_t)(m0 + ml) * 256 + n]);
                            fl[ml * 64 + (nl ^ (ml & 63))] = v;
                        }
            }
            __syncthreads();
            for (int r = tid >> 6; r < 128; r += 4) {      // 128 runs of 64 contiguous floats
                int nl = r & 63, tl2 = r >> 6;
                int token = tl2 * 64 + lane;
                outT[(size_t)bfi * 1048576 + (size_t)(n0 + p * 64 + nl) * 4096 +
                     (size_t)(hbase + tl2) * 64 + lane] = fl[token * 64 + (nl ^ (token & 63))];
            }
        }
        return;
    }

    // modes 0/1/2: wave-private LDS repack (8KB/wave), then coalesced 16B stores.
    unsigned short* ls = (unsigned short*)(smem + wvid * 8192);   // [64 rows][8 granules x 8 shorts]
    float biasv[4];
    #pragma unroll
    for (int j = 0; j < 4; ++j) biasv[j] = bias[n0 + wn * 64 + j * 16 + r16];
    const unsigned short* resp = res + (size_t)(m0 + wm * 64) * ldc + n0 + wn * 64;  // only read if mode==1
    #pragma unroll
    for (int i = 0; i < 4; ++i) {
        #pragma unroll
        for (int r = 0; r < 4; ++r) {
            int row = i * 16 + kg * 4 + r;
            #pragma unroll
            for (int j = 0; j < 4; ++j) {
                float v = acc[i][j][r] + biasv[j];
                if (mode == 1) v += bf2f(resp[(size_t)row * ldc + j * 16 + r16]);
                else if (mode == 2) v = gelu_fast(v);
                int col = j * 16 + r16;
                ls[row * 64 + (((col >> 3) ^ (row & 7)) * 8) + (col & 7)] = f2bf(v);
            }
        }
    }
    // wave-synchronous: LDS ops from a wave execute in order; no barrier needed.
    unsigned short* Cw = C + (size_t)(m0 + wm * 64) * ldc + n0 + wn * 64;
    int p8 = lane & 7;
    #pragma unroll
    for (int t = 0; t < 8; ++t) {
        int row = t * 8 + (lane >> 3);
        int g = p8 ^ (row & 7);
        uint4 d4 = *(const uint4*)&ls[row * 64 + g * 8];
        *(uint4*)&Cw[(size_t)row * ldc + p8 * 8] = d4;
    }
}

// ---------------- attention (both directions, one launch): per (dir, b, head, line) ----------------
__global__ __launch_bounds__(256) void attn_kernel(const unsigned short* __restrict__ qkvH,
                                                   const unsigned short* __restrict__ qkvV,
                                                   unsigned short* __restrict__ ao) {
    __shared__ unsigned short qL[5 * 1024], kL[5 * 1024], vL[5 * 1024];
    __shared__ float sL[25];
    int g = blockIdx.x;
    int vertical = g >> 10;
    const unsigned short* qkv = vertical ? qkvV : qkvH;
    int lw = g & 63;            // h (horizontal) or w (vertical)
    int head = (g >> 6) & 7;
    int b = (g >> 9) & 1;
    int tid = threadIdx.x;
    // staging: 640 chunks of 8 bf16 (16B) per tensor
    for (int c = tid; c < 640; c += 256) {
        int f = c >> 7, rem = c & 127;
        int pos = rem >> 1, d0 = (rem & 1) * 8;
        size_t n = (size_t)b * 20480 + (size_t)f * 4096 +
                   (vertical ? (pos * 64 + lw) : (lw * 64 + pos));
        size_t src = n * 384 + head * 16 + d0;
        *(uint4*)&qL[c * 8] = *(const uint4*)&qkv[src];
        *(uint4*)&kL[c * 8] = *(const uint4*)&qkv[src + 128];
        *(uint4*)&vL[c * 8] = *(const uint4*)&qkv[src + 256];
    }
    __syncthreads();
    int lane = tid & 63, wwv = tid >> 6;
    for (int p = wwv; p < 25; p += 4) {
        int qf = p / 5, kf = p - qf * 5;
        float acc = 0.f;
        const unsigned short* qp = &qL[qf * 1024 + lane * 16];
        const unsigned short* kp = &kL[kf * 1024 + lane * 16];
        #pragma unroll
        for (int t = 0; t < 16; ++t) acc += bf2f(qp[t]) * bf2f(kp[t]);
        for (int off = 32; off; off >>= 1) acc += __shfl_down(acc, off);
        if (lane == 0) sL[p] = acc * 0.03125f;   // 1/sqrt(1024)
    }
    __syncthreads();
    if (tid < 5) {
        float mx = -1e30f;
        for (int kf = 0; kf < 5; ++kf) mx = fmaxf(mx, sL[tid * 5 + kf]);
        float e[5], sum = 0.f;
        for (int kf = 0; kf < 5; ++kf) { e[kf] = expf(sL[tid * 5 + kf] - mx); sum += e[kf]; }
        float inv = 1.f / sum;
        for (int kf = 0; kf < 5; ++kf) sL[tid * 5 + kf] = e[kf] * inv;
    }
    __syncthreads();
    int coff = vertical ? 128 : 0;
    for (int c = tid; c < 640; c += 256) {
        int qf = c >> 7, rem = c & 127;
        int pos = rem >> 1, d0 = (rem & 1) * 8;
        float accv[8] = {};
        #pragma unroll
        for (int kf = 0; kf < 5; ++kf) {
            float w = sL[qf * 5 + kf];
            const unsigned short* vp = &vL[kf * 1024 + rem * 8];
            #pragma unroll
            for (int e = 0; e < 8; ++e) accv[e] += w * bf2f(vp[e]);
        }
        unsigned short pk[8];
        #pragma unroll
        for (int e = 0; e < 8; ++e) pk[e] = f2bf(accv[e]);
        size_t n = (size_t)b * 20480 + (size_t)qf * 4096 +
                   (vertical ? (pos * 64 + lw) : (lw * 64 + pos));
        *(uint4*)&ao[n * 256 + coff + head * 16 + d0] = *(const uint4*)pk;
    }
}

// ---------------- LN2: y bf16 (N,256) -> tn bf16 (N,256), one wave per token ----------------
__global__ __launch_bounds__(256) void ln2_kernel(const unsigned short* __restrict__ y,
                                                  const float* __restrict__ g,
                                                  const float* __restrict__ bta,
                                                  unsigned short* __restrict__ tn) {
    int tid = threadIdx.x;
    int lane = tid & 63, wvid = tid >> 6;
    int token = blockIdx.x * 4 + wvid;
    const unsigned short* yp = y + (size_t)token * 256;
    uint2 raw = *(const uint2*)&yp[lane * 4];
    unsigned short rs[4];
    *(uint2*)rs = raw;
    float v[4];
    #pragma unroll
    for (int e = 0; e < 4; ++e) v[e] = bf2f(rs[e]);
    float s = v[0] + v[1] + v[2] + v[3];
    float sq = v[0] * v[0] + v[1] * v[1] + v[2] * v[2] + v[3] * v[3];
    for (int off = 32; off; off >>= 1) { s += __shfl_xor(s, off); sq += __shfl_xor(sq, off); }
    float mean = s * (1.f / 256.f);
    float var = sq * (1.f / 256.f) - mean * mean;
    float rstd = rsqrtf(var + 1e-5f);
    unsigned short* tp = tn + (size_t)token * 256;
    unsigned short o[4];
    #pragma unroll
    for (int e = 0; e < 4; ++e) {
        int c = lane * 4 + e;
        o[e] = f2bf((v[e] - mean) * rstd * g[c] + bta[c]);
    }
    *(uint2*)&tp[lane * 4] = *(const uint2*)o;
}

extern "C" void kernel_launch(void* const* d_in, const int* in_sizes, int n_in,
                              void* d_out, int out_size, void* d_ws, size_t ws_size,
                              hipStream_t stream) {
    (void)in_sizes; (void)n_in; (void)out_size; (void)ws_size;
    const float* x    = (const float*)d_in[0];
    const float* ln1g = (const float*)d_in[1];
    const float* ln1b = (const float*)d_in[2];
    const float* wh   = (const float*)d_in[3];
    const float* bh   = (const float*)d_in[4];
    const float* wv   = (const float*)d_in[5];
    const float* bv   = (const float*)d_in[6];
    const float* wf   = (const float*)d_in[7];
    const float* bfp  = (const float*)d_in[8];
    const float* ln2g = (const float*)d_in[9];
    const float* ln2b = (const float*)d_in[10];
    const float* w1   = (const float*)d_in[11];
    const float* b1   = (const float*)d_in[12];
    const float* w2   = (const float*)d_in[13];
    const float* b2   = (const float*)d_in[14];
    float* out = (float*)d_out;
    char* ws = (char*)d_ws;

    // workspace layout (total ~148.4 MB)
    unsigned short* whb = (unsigned short*)(ws + 0);
    unsigned short* wvb = (unsigned short*)(ws + 98304);
    unsigned short* wfb = (unsigned short*)(ws + 196608);
    unsigned short* w1b = (unsigned short*)(ws + 327680);
    unsigned short* w2b = (unsigned short*)(ws + 851968);
    const size_t off = 1572864;
    unsigned short* xn   = (unsigned short*)(ws + off);                    // 21.0 MB (reused as tn)
    unsigned short* xt   = (unsigned short*)(ws + off + 20971520ull);      // 21.0 MB
    unsigned short* qkvh = (unsigned short*)(ws + off + 41943040ull);      // 31.5 MB (hid part 1)
    unsigned short* qkvv = (unsigned short*)(ws + off + 73400320ull);      // 31.5 MB (hid part 2)
    unsigned short* ao   = (unsigned short*)(ws + off + 104857600ull);     // 21.0 MB (hid part 3)
    unsigned short* yb   = (unsigned short*)(ws + off + 125829120ull);     // 21.0 MB
    unsigned short* tnb  = xn;
    unsigned short* hid  = qkvh;   // hid (N x 1024, 84 MB) overlays qkvh/qkvv/ao (dead by FFN1)

    cvt_all_kernel<<<2688, 256, 0, stream>>>(wh, wv, wf, w1, w2, whb, wvb, wfb, w1b, w2b);

    ln1_kernel<<<640, 256, 0, stream>>>(x, ln1g, ln1b, xn, xt);

    // QKV projections: (N x 128) @ (384 x 128)^T
    gemm128_kernel<<<dim3(3, 320), 256, 0, stream>>>(xn,       256, whb, bh, qkvh, 384, nullptr, nullptr, 128, 0);
    gemm128_kernel<<<dim3(3, 320), 256, 0, stream>>>(xn + 128, 256, wvb, bv, qkvv, 384, nullptr, nullptr, 128, 0);

    attn_kernel<<<2048, 256, 0, stream>>>(qkvh, qkvv, ao);

    // proj + residual: y = ao @ wf^T + bf + x
    gemm128_kernel<<<dim3(2, 320), 256, 0, stream>>>(ao, 256, wfb, bfp, yb, 256, xt, nullptr, 256, 1);

    ln2_kernel<<<10240, 256, 0, stream>>>(yb, ln2g, ln2b, tnb);

    // FFN1: hid = gelu(tn @ w1^T + b1)
    gemm128_kernel<<<dim3(8, 320), 256, 0, stream>>>(tnb, 256, w1b, b1, hid, 1024, nullptr, nullptr, 256, 2);
    // FFN2 + residual + transpose: out = (y + hid @ w2^T + b2) -> (B,F,C,H,W) fp32
    gemm128_kernel<<<dim3(2, 320), 256, 0, stream>>>(hid, 1024, w2b, b2, nullptr, 256, yb, out, 1024, 3);
}

// Round 7
// 324.491 us; speedup vs baseline: 1.1928x; 1.0496x over previous
//
#include <hip/hip_runtime.h>
#include <cstdint>
#include <cmath>

// Problem constants: B=2, F=5, C=256, H=64, W=64, HN=8, hd=16
// Token layout: n = (b*5+f)*4096 + h*64 + w, N = 40960 tokens, channels-last.

typedef __bf16 bf16x8 __attribute__((ext_vector_type(8)));
typedef float f32x4 __attribute__((ext_vector_type(4)));

__device__ __forceinline__ unsigned short f2bf(float f) {
    union { float f; unsigned int u; } v; v.f = f;
    unsigned int r = (v.u + 0x7fffu + ((v.u >> 16) & 1u)) >> 16;
    return (unsigned short)r;
}
__device__ __forceinline__ float bf2f(unsigned short h) {
    union { unsigned int u; float f; } v; v.u = ((unsigned int)h) << 16;
    return v.f;
}
// tanh-form GELU, fully inline: x*sigmoid(2z), z = x*(c0 + c1*x^2)
__device__ __forceinline__ float gelu_fast(float x) {
    float z2 = 2.8853900817779268f * x * (0.7978845608028654f + 0.0356774081363001f * x * x);
    float u = __builtin_amdgcn_exp2f(z2);       // v_exp_f32
    return x - x * __builtin_amdgcn_rcpf(1.0f + u);
}

// async global->LDS, 16B per lane; LDS dest = wave-uniform base + lane*16
__device__ __forceinline__ void gld16(const unsigned short* g, unsigned short* l) {
    __builtin_amdgcn_global_load_lds(
        (const __attribute__((address_space(1))) void*)g,
        (__attribute__((address_space(3))) void*)l, 16, 0, 0);
}

// ---------------- fused weight fp32 -> bf16 (all 5 weights, one launch) ----------------
__global__ __launch_bounds__(256) void cvt_all_kernel(
        const float* __restrict__ wh, const float* __restrict__ wv,
        const float* __restrict__ wf, const float* __restrict__ w1,
        const float* __restrict__ w2,
        unsigned short* __restrict__ whb, unsigned short* __restrict__ wvb,
        unsigned short* __restrict__ wfb, unsigned short* __restrict__ w1b,
        unsigned short* __restrict__ w2b) {
    int i = blockIdx.x * 256 + threadIdx.x;   // grid covers 688128 exactly
    const float* s; unsigned short* d; int j;
    if (i < 49152)       { s = wh; d = whb; j = i; }
    else if (i < 98304)  { s = wv; d = wvb; j = i - 49152; }
    else if (i < 163840) { s = wf; d = wfb; j = i - 98304; }
    else if (i < 425984) { s = w1; d = w1b; j = i - 163840; }
    else                 { s = w2; d = w2b; j = i - 425984; }
    d[j] = f2bf(s[j]);
}

// ---------------- fused LN1 + QKV(h&v): one block per (bf, h) line (64 tokens) ----------------
// Phase 1: LN1 stats + raw transpose into LDS (stride 264). Writes xt (raw bf16).
// Phase 2: normalize A-tile in place.
// Phase 3: 6 n-tiles (3 for wh -> qkvh, 3 for wv -> qkvv), A resident, B staged
//          BK=64 via global_load_lds with XOR k-seg swizzle.
__global__ __launch_bounds__(256) void ln1qkv_kernel(
        const float* __restrict__ x,
        const float* __restrict__ g, const float* __restrict__ bta,
        const unsigned short* __restrict__ whb, const float* __restrict__ bh,
        const unsigned short* __restrict__ wvb, const float* __restrict__ bv,
        unsigned short* __restrict__ xt,
        unsigned short* __restrict__ qkvh, unsigned short* __restrict__ qkvv) {
    __shared__ __align__(16) unsigned short At[64 * 264];   // 33792 B, [token][ch] padded
    __shared__ __align__(16) unsigned short Bs[128 * 64];   // 16384 B, one BK=64 B-tile
    __shared__ float psum[4][64], psq[4][64], meanL[64], rstdL[64];
    __shared__ float gg[256], bb[256];

    int bx = blockIdx.x;
    int bf = bx >> 6, h = bx & 63;
    size_t base = (size_t)bf * 1048576 + (size_t)h * 64;
    int tid = threadIdx.x;
    int w = tid & 63, cg = tid >> 6;
    // phase 1: strided fp32 read, raw bf16 transpose into LDS, per-token stats
    float s = 0.f, sq = 0.f;
    for (int k = 0; k < 64; ++k) {
        int c = cg * 64 + k;
        float v = x[base + (size_t)c * 4096 + w];
        s += v; sq += v * v;
        At[w * 264 + c] = f2bf(v);
    }
    psum[cg][w] = s; psq[cg][w] = sq;
    gg[tid] = g[tid]; bb[tid] = bta[tid];
    __syncthreads();
    if (tid < 64) {
        float ss = psum[0][tid] + psum[1][tid] + psum[2][tid] + psum[3][tid];
        float qq = psq[0][tid] + psq[1][tid] + psq[2][tid] + psq[3][tid];
        float mean = ss * (1.f / 256.f);
        float var = qq * (1.f / 256.f) - mean * mean;
        meanL[tid] = mean;
        rstdL[tid] = rsqrtf(var + 1e-5f);
    }
    __syncthreads();
    int n0g = bf * 4096 + h * 64;                 // first token of this line
    // phase 2: per 8-ch chunk: write xt (raw), normalize in place
    for (int t = 0; t < 8; ++t) {
        int idx = t * 256 + tid;                  // 2048 chunks
        int tok = idx >> 5, cc = idx & 31;
        unsigned short raw[8];
        *(uint4*)raw = *(const uint4*)&At[tok * 264 + cc * 8];
        *(uint4*)&xt[(size_t)(n0g + tok) * 256 + cc * 8] = *(const uint4*)raw;
        float mean = meanL[tok], rstd = rstdL[tok];
        unsigned short nm[8];
        #pragma unroll
        for (int e = 0; e < 8; ++e) {
            int ch = cc * 8 + e;
            nm[e] = f2bf((bf2f(raw[e]) - mean) * rstd * gg[ch] + bb[ch]);
        }
        *(uint4*)&At[tok * 264 + cc * 8] = *(const uint4*)nm;
    }
    __syncthreads();

    // phase 3: GEMM. 4 waves, wave nq covers out-cols nq*32..+31 of each 128-wide n-tile.
    int lane = tid & 63, wvid = tid >> 6;
    int r16 = lane & 15, kg = lane >> 4;
    int srow = wvid * 8 + (lane >> 3);
    int segg = (lane & 7) ^ (lane >> 3);          // global-side k-seg swizzle
    unsigned short* lB = Bs + wvid * 512;
    for (int t = 0; t < 6; ++t) {
        const unsigned short* Wt; const float* bias; unsigned short* dst; int ot, aoff;
        if (t < 3) { Wt = whb + t * 16384;       bias = bh + t * 128;       dst = qkvh; ot = t * 128;       aoff = 0; }
        else       { Wt = wvb + (t - 3) * 16384; bias = bv + (t - 3) * 128; dst = qkvv; ot = (t - 3) * 128; aoff = 128; }
        f32x4 acc[4][2] = {};
        for (int kk = 0; kk < 2; ++kk) {
            const unsigned short* pB = Wt + (size_t)srow * 128 + kk * 64 + segg * 8;
            #pragma unroll
            for (int i = 0; i < 4; ++i)
                gld16(pB + (size_t)i * 32 * 128, lB + i * 2048);
            __syncthreads();
            #pragma unroll
            for (int tt = 0; tt < 2; ++tt) {
                int ka = aoff + kk * 64 + (tt * 4 + kg) * 8;
                int ss = ((tt * 4 + kg) ^ (r16 & 7)) * 8;
                bf16x8 af[4], bfr[2];
                #pragma unroll
                for (int i = 0; i < 4; ++i)
                    af[i] = *(const bf16x8*)&At[(i * 16 + r16) * 264 + ka];
                #pragma unroll
                for (int j = 0; j < 2; ++j)
                    bfr[j] = *(const bf16x8*)&Bs[(wvid * 32 + j * 16 + r16) * 64 + ss];
                #pragma unroll
                for (int i = 0; i < 4; ++i)
                    #pragma unroll
                    for (int j = 0; j < 2; ++j)
                        acc[i][j] = __builtin_amdgcn_mfma_f32_16x16x32_bf16(af[i], bfr[j], acc[i][j], 0, 0, 0);
            }
            __syncthreads();
        }
        float biasv[2];
        #pragma unroll
        for (int j = 0; j < 2; ++j) biasv[j] = bias[wvid * 32 + j * 16 + r16];
        #pragma unroll
        for (int i = 0; i < 4; ++i)
            #pragma unroll
            for (int j = 0; j < 2; ++j)
                #pragma unroll
                for (int r = 0; r < 4; ++r) {
                    int m = i * 16 + kg * 4 + r;                  // token within line
                    int nc = ot + wvid * 32 + j * 16 + r16;       // out channel (0..383)
                    dst[(size_t)(n0g + m) * 384 + nc] = f2bf(acc[i][j][r] + biasv[j]);
                }
    }
}

// ---------------- 128x128 MFMA GEMM: C(MxN) = A(MxK) * B(NxK)^T (+epilogue) ----------------
// modes: 1 = bias + res(bf16, ldc), store bf16         (attn proj + x residual)
//        2 = bias + fast GELU, store bf16              (FFN1)
//        3 = bias + res(bf16,256), store fp32 transposed to (B,F,C,H,W) via LDS (FFN2)
__global__ __launch_bounds__(256) void gemm128_kernel(
        const unsigned short* __restrict__ A, int lda,
        const unsigned short* __restrict__ B,
        const float* __restrict__ bias,
        unsigned short* __restrict__ C, int ldc,
        const unsigned short* __restrict__ res,
        float* __restrict__ outT,
        int K, int mode) {
    __shared__ __align__(16) unsigned char smem[32768];   // As 16KB | Bs 16KB ; mode3 reuses as fp32 buf
    unsigned short* As = (unsigned short*)smem;
    unsigned short* Bs = (unsigned short*)(smem + 16384);

    int tid = threadIdx.x;
    int lane = tid & 63, wvid = tid >> 6;
    int wm = wvid >> 1, wn = wvid & 1;
    int r16 = lane & 15, kg = lane >> 4;

    // XCD-aware remap
    int nx = gridDim.x;
    int L = blockIdx.y * nx + blockIdx.x;
    int T = nx * gridDim.y;
    int newL = (T & 7) ? L : ((L & 7) * (T >> 3) + (L >> 3));
    int nt = newL % nx, mt = newL / nx;
    int m0 = mt * 128, n0 = nt * 128;

    int srow = wvid * 8 + (lane >> 3);
    int segg = (lane & 7) ^ (lane >> 3);
    const unsigned short* pA = A + (size_t)(m0 + srow) * lda + segg * 8;
    const unsigned short* pB = B + (size_t)(n0 + srow) * K + segg * 8;
    unsigned short* lA = As + wvid * 512;
    unsigned short* lB = Bs + wvid * 512;

    f32x4 acc[4][4] = {};
    for (int k0 = 0; k0 < K; k0 += 64) {
        #pragma unroll
        for (int i = 0; i < 4; ++i) {
            gld16(pA + (size_t)i * 32 * lda, lA + i * 2048);
            gld16(pB + (size_t)i * 32 * K,  lB + i * 2048);
        }
        pA += 64; pB += 64;
        __syncthreads();
        #pragma unroll
        for (int t = 0; t < 2; ++t) {
            bf16x8 af[4], bfr[4];
            int ss = ((t * 4 + kg) ^ (r16 & 7)) * 8;
            #pragma unroll
            for (int i = 0; i < 4; ++i) {
                af[i]  = *(const bf16x8*)&As[(wm * 64 + i * 16 + r16) * 64 + ss];
                bfr[i] = *(const bf16x8*)&Bs[(wn * 64 + i * 16 + r16) * 64 + ss];
            }
            #pragma unroll
            for (int i = 0; i < 4; ++i)
                #pragma unroll
                for (int j = 0; j < 4; ++j)
                    acc[i][j] = __builtin_amdgcn_mfma_f32_16x16x32_bf16(af[i], bfr[j], acc[i][j], 0, 0, 0);
        }
        __syncthreads();
    }

    if (mode == 3) {
        float* fl = (float*)smem;               // [128 tokens][64] fp32, XOR col swizzle
        int bfi = m0 >> 12;
        int hbase = (m0 >> 6) & 63;
        for (int p = 0; p < 2; ++p) {
            __syncthreads();
            if (wn == p) {
                #pragma unroll
                for (int i = 0; i < 4; ++i)
                    #pragma unroll
                    for (int j = 0; j < 4; ++j)
                        #pragma unroll
                        for (int r = 0; r < 4; ++r) {
                            int ml = wm * 64 + i * 16 + kg * 4 + r;
                            int nl = j * 16 + r16;
                            int n = n0 + p * 64 + nl;
                            float v = acc[i][j][r] + bias[n] + bf2f(res[(size_t)(m0 + ml) * 256 + n]);
                            fl[ml * 64 + (nl ^ (ml & 63))] = v;
                        }
            }
            __syncthreads();
            for (int r = tid >> 6; r < 128; r += 4) {
                int nl = r & 63, tl2 = r >> 6;
                int token = tl2 * 64 + lane;
                outT[(size_t)bfi * 1048576 + (size_t)(n0 + p * 64 + nl) * 4096 +
                     (size_t)(hbase + tl2) * 64 + lane] = fl[token * 64 + (nl ^ (token & 63))];
            }
        }
        return;
    }
    // direct-store epilogue (R5 style, hoisted bias)
    float biasv[4];
    #pragma unroll
    for (int j = 0; j < 4; ++j) biasv[j] = bias[n0 + wn * 64 + j * 16 + r16];
    #pragma unroll
    for (int i = 0; i < 4; ++i)
        #pragma unroll
        for (int j = 0; j < 4; ++j)
            #pragma unroll
            for (int r = 0; r < 4; ++r) {
                int m = m0 + wm * 64 + i * 16 + kg * 4 + r;
                int n = n0 + wn * 64 + j * 16 + r16;
                float v = acc[i][j][r] + biasv[j];
                if (mode == 1) v += bf2f(res[(size_t)m * ldc + n]);
                else if (mode == 2) v = gelu_fast(v);
                C[(size_t)m * ldc + n] = f2bf(v);
            }
}

// ---------------- attention (both directions, one launch): per (dir, b, head, line) ----------------
__global__ __launch_bounds__(256) void attn_kernel(const unsigned short* __restrict__ qkvH,
                                                   const unsigned short* __restrict__ qkvV,
                                                   unsigned short* __restrict__ ao) {
    __shared__ unsigned short qL[5 * 1024], kL[5 * 1024], vL[5 * 1024];
    __shared__ float sL[25];
    int g = blockIdx.x;
    int vertical = g >> 10;
    const unsigned short* qkv = vertical ? qkvV : qkvH;
    int lw = g & 63;
    int head = (g >> 6) & 7;
    int b = (g >> 9) & 1;
    int tid = threadIdx.x;
    for (int c = tid; c < 640; c += 256) {
        int f = c >> 7, rem = c & 127;
        int pos = rem >> 1, d0 = (rem & 1) * 8;
        size_t n = (size_t)b * 20480 + (size_t)f * 4096 +
                   (vertical ? (pos * 64 + lw) : (lw * 64 + pos));
        size_t src = n * 384 + head * 16 + d0;
        *(uint4*)&qL[c * 8] = *(const uint4*)&qkv[src];
        *(uint4*)&kL[c * 8] = *(const uint4*)&qkv[src + 128];
        *(uint4*)&vL[c * 8] = *(const uint4*)&qkv[src + 256];
    }
    __syncthreads();
    int lane = tid & 63, wwv = tid >> 6;
    for (int p = wwv; p < 25; p += 4) {
        int qf = p / 5, kf = p - qf * 5;
        float acc = 0.f;
        const unsigned short* qp = &qL[qf * 1024 + lane * 16];
        const unsigned short* kp = &kL[kf * 1024 + lane * 16];
        #pragma unroll
        for (int t = 0; t < 16; ++t) acc += bf2f(qp[t]) * bf2f(kp[t]);
        for (int off = 32; off; off >>= 1) acc += __shfl_down(acc, off);
        if (lane == 0) sL[p] = acc * 0.03125f;   // 1/sqrt(1024)
    }
    __syncthreads();
    if (tid < 5) {
        float mx = -1e30f;
        for (int kf = 0; kf < 5; ++kf) mx = fmaxf(mx, sL[tid * 5 + kf]);
        float e[5], sum = 0.f;
        for (int kf = 0; kf < 5; ++kf) { e[kf] = expf(sL[tid * 5 + kf] - mx); sum += e[kf]; }
        float inv = 1.f / sum;
        for (int kf = 0; kf < 5; ++kf) sL[tid * 5 + kf] = e[kf] * inv;
    }
    __syncthreads();
    int coff = vertical ? 128 : 0;
    for (int c = tid; c < 640; c += 256) {
        int qf = c >> 7, rem = c & 127;
        int pos = rem >> 1, d0 = (rem & 1) * 8;
        float accv[8] = {};
        #pragma unroll
        for (int kf = 0; kf < 5; ++kf) {
            float w = sL[qf * 5 + kf];
            const unsigned short* vp = &vL[kf * 1024 + rem * 8];
            #pragma unroll
            for (int e = 0; e < 8; ++e) accv[e] += w * bf2f(vp[e]);
        }
        unsigned short pk[8];
        #pragma unroll
        for (int e = 0; e < 8; ++e) pk[e] = f2bf(accv[e]);
        size_t n = (size_t)b * 20480 + (size_t)qf * 4096 +
                   (vertical ? (pos * 64 + lw) : (lw * 64 + pos));
        *(uint4*)&ao[n * 256 + coff + head * 16 + d0] = *(const uint4*)pk;
    }
}

// ---------------- LN2: y bf16 (N,256) -> tn bf16 (N,256), one wave per token ----------------
__global__ __launch_bounds__(256) void ln2_kernel(const unsigned short* __restrict__ y,
                                                  const float* __restrict__ g,
                                                  const float* __restrict__ bta,
                                                  unsigned short* __restrict__ tn) {
    int tid = threadIdx.x;
    int lane = tid & 63, wvid = tid >> 6;
    int token = blockIdx.x * 4 + wvid;
    const unsigned short* yp = y + (size_t)token * 256;
    uint2 raw = *(const uint2*)&yp[lane * 4];
    unsigned short rs[4];
    *(uint2*)rs = raw;
    float v[4];
    #pragma unroll
    for (int e = 0; e < 4; ++e) v[e] = bf2f(rs[e]);
    float s = v[0] + v[1] + v[2] + v[3];
    float sq = v[0] * v[0] + v[1] * v[1] + v[2] * v[2] + v[3] * v[3];
    for (int off = 32; off; off >>= 1) { s += __shfl_xor(s, off); sq += __shfl_xor(sq, off); }
    float mean = s * (1.f / 256.f);
    float var = sq * (1.f / 256.f) - mean * mean;
    float rstd = rsqrtf(var + 1e-5f);
    unsigned short* tp = tn + (size_t)token * 256;
    unsigned short o[4];
    #pragma unroll
    for (int e = 0; e < 4; ++e) {
        int c = lane * 4 + e;
        o[e] = f2bf((v[e] - mean) * rstd * g[c] + bta[c]);
    }
    *(uint2*)&tp[lane * 4] = *(const uint2*)o;
}

extern "C" void kernel_launch(void* const* d_in, const int* in_sizes, int n_in,
                              void* d_out, int out_size, void* d_ws, size_t ws_size,
                              hipStream_t stream) {
    (void)in_sizes; (void)n_in; (void)out_size; (void)ws_size;
    const float* x    = (const float*)d_in[0];
    const float* ln1g = (const float*)d_in[1];
    const float* ln1b = (const float*)d_in[2];
    const float* wh   = (const float*)d_in[3];
    const float* bh   = (const float*)d_in[4];
    const float* wv   = (const float*)d_in[5];
    const float* bv   = (const float*)d_in[6];
    const float* wf   = (const float*)d_in[7];
    const float* bfp  = (const float*)d_in[8];
    const float* ln2g = (const float*)d_in[9];
    const float* ln2b = (const float*)d_in[10];
    const float* w1   = (const float*)d_in[11];
    const float* b1   = (const float*)d_in[12];
    const float* w2   = (const float*)d_in[13];
    const float* b2   = (const float*)d_in[14];
    float* out = (float*)d_out;
    char* ws = (char*)d_ws;

    // workspace layout (total ~148.4 MB)
    unsigned short* whb = (unsigned short*)(ws + 0);
    unsigned short* wvb = (unsigned short*)(ws + 98304);
    unsigned short* wfb = (unsigned short*)(ws + 196608);
    unsigned short* w1b = (unsigned short*)(ws + 327680);
    unsigned short* w2b = (unsigned short*)(ws + 851968);
    const size_t off = 1572864;
    unsigned short* tnb  = (unsigned short*)(ws + off);                    // 21.0 MB
    unsigned short* xt   = (unsigned short*)(ws + off + 20971520ull);      // 21.0 MB
    unsigned short* qkvh = (unsigned short*)(ws + off + 41943040ull);      // 31.5 MB (hid part 1)
    unsigned short* qkvv = (unsigned short*)(ws + off + 73400320ull);      // 31.5 MB (hid part 2)
    unsigned short* ao   = (unsigned short*)(ws + off + 104857600ull);     // 21.0 MB (hid part 3)
    unsigned short* yb   = (unsigned short*)(ws + off + 125829120ull);     // 21.0 MB
    unsigned short* hid  = qkvh;   // hid (N x 1024, 84 MB) overlays qkvh/qkvv/ao (dead by FFN1)

    cvt_all_kernel<<<2688, 256, 0, stream>>>(wh, wv, wf, w1, w2, whb, wvb, wfb, w1b, w2b);

    // fused LN1 + QKV (both halves): writes xt, qkvh, qkvv
    ln1qkv_kernel<<<640, 256, 0, stream>>>(x, ln1g, ln1b, whb, bh, wvb, bv, xt, qkvh, qkvv);

    attn_kernel<<<2048, 256, 0, stream>>>(qkvh, qkvv, ao);

    // proj + residual: y = ao @ wf^T + bf + x
    gemm128_kernel<<<dim3(2, 320), 256, 0, stream>>>(ao, 256, wfb, bfp, yb, 256, xt, nullptr, 256, 1);

    ln2_kernel<<<10240, 256, 0, stream>>>(yb, ln2g, ln2b, tnb);

    // FFN1: hid = gelu(tn @ w1^T + b1)
    gemm128_kernel<<<dim3(8, 320), 256, 0, stream>>>(tnb, 256, w1b, b1, hid, 1024, nullptr, nullptr, 256, 2);
    // FFN2 + residual + transpose: out = (y + hid @ w2^T + b2) -> (B,F,C,H,W) fp32
    gemm128_kernel<<<dim3(2, 320), 256, 0, stream>>>(hid, 1024, w2b, b2, nullptr, 256, yb, out, 1024, 3);
}